// Round 7
// baseline (147.267 us; speedup 1.0000x reference)
//
#include <hip/hip_runtime.h>
#include <hip/hip_bf16.h>

#define B_    8
#define CIN   64
#define COUT  64
#define RN_   4
#define H_    128
#define W_    128
#define HW_   (H_ * W_)
#define BN_EPS 1e-5f

typedef short v8s __attribute__((ext_vector_type(8)));
typedef float v4f __attribute__((ext_vector_type(4)));

__device__ __forceinline__ unsigned short f2bf(float f) {
    unsigned int u = __float_as_uint(f);
    u += 0x7FFFu + ((u >> 16) & 1u);       // round-to-nearest-even
    return (unsigned short)(u >> 16);
}

// ---------------------------------------------------------------------------
// prep: merged transpose kernels (one launch)
//   blocks [0,1024):    x fp32 [b][c][h][w] -> xT bf16 [b][h][w][c]
//   blocks [1024,1152): kernel fp32 -> kT bf16 in MFMA A-fragment order
//   block  1152:        mask weights fp32 [r][c][t] -> mwT bf16 in A-frag
//                       order (region replicated to rows r, r+4, r+8, r+12)
// ---------------------------------------------------------------------------
__global__ __launch_bounds__(256) void prep(const float* __restrict__ x,
                                            const float* __restrict__ kr,
                                            const float* __restrict__ mw,
                                            unsigned short* __restrict__ xT,
                                            unsigned short* __restrict__ kT,
                                            unsigned short* __restrict__ mwT) {
    __shared__ float sl[16 * 64 * 9];                 // 36 KB (union of both uses)
    if (blockIdx.x < 1024) {
        const int b = blockIdx.x >> 7, h = blockIdx.x & 127;
        const float* xp = x + (size_t)b * CIN * HW_ + (size_t)h * W_;
        for (int idx = threadIdx.x; idx < CIN * (W_ / 4); idx += 256) {
            const int c = idx >> 5, w4 = (idx & 31) << 2;   // float4 loads (G13)
            const float4 v = *(const float4*)(xp + (size_t)c * HW_ + w4);
            float* s = &sl[c * 129 + w4];                   // 129-pad: conflict-free col reads
            s[0] = v.x; s[1] = v.y; s[2] = v.z; s[3] = v.w;
        }
        __syncthreads();
        unsigned short* op = xT + ((size_t)b * H_ + h) * (W_ * CIN);
        for (int idx = threadIdx.x; idx < (W_ * CIN) / 8; idx += 256) {
            const int w = idx >> 3, c0 = (idx & 7) << 3;
            int4 v;
            v.x = f2bf(sl[(c0 + 0) * 129 + w]) | ((unsigned)f2bf(sl[(c0 + 1) * 129 + w]) << 16);
            v.y = f2bf(sl[(c0 + 2) * 129 + w]) | ((unsigned)f2bf(sl[(c0 + 3) * 129 + w]) << 16);
            v.z = f2bf(sl[(c0 + 4) * 129 + w]) | ((unsigned)f2bf(sl[(c0 + 5) * 129 + w]) << 16);
            v.w = f2bf(sl[(c0 + 6) * 129 + w]) | ((unsigned)f2bf(sl[(c0 + 7) * 129 + w]) << 16);
            *(int4*)(op + (w << 6) + c0) = v;
        }
    } else if (blockIdx.x < 1152) {
        const int bid = blockIdx.x - 1024;
        const int br = bid >> 2, oq = bid & 3;        // br = b*4+r; oq = 16-o chunk
        const float* src = kr + ((size_t)br * 64 + oq * 16) * (64 * 9);
        for (int idx = threadIdx.x; idx < 2304; idx += 256)
            *(float4*)&sl[idx << 2] = *(const float4*)&src[idx << 2];
        __syncthreads();
        unsigned short* dst = kT + (size_t)br * (9 * 4096);
        for (int idx = threadIdx.x; idx < 1152; idx += 256) {
            const int t = idx >> 7, rem = idx & 127, o16 = rem >> 3, c8 = (rem & 7) << 3;
            unsigned short s[8];
            #pragma unroll
            for (int j = 0; j < 8; j++)
                s[j] = f2bf(sl[(o16 * 64 + c8 + j) * 9 + t]);
            int4 v;
            v.x = s[0] | ((unsigned)s[1] << 16);
            v.y = s[2] | ((unsigned)s[3] << 16);
            v.z = s[4] | ((unsigned)s[5] << 16);
            v.w = s[6] | ((unsigned)s[7] << 16);
            // fragment order: o = oq*16+o16 -> fm=oq, i=o16 ; c = c8+j -> ks=c8>>5, g=(c8>>3)&3
            const int q  = oq * 2 + (c8 >> 5);        // frag index fm*2+ks
            const int gg = (c8 >> 3) & 3;             // g
            *(int4*)(dst + (size_t)t * 4096 + q * 512 + (gg * 16 + o16) * 8) = v;
        }
    } else {
        // mwT[tile=tap*2+ks][lane][8]: lane=(g<<4)|i, row i holds region i&3
        for (int idx = threadIdx.x; idx < 9 * 2 * 64 * 8; idx += 256) {
            const int tile = idx >> 9;                // tap*2+ks
            const int tap = tile >> 1, ks = tile & 1;
            const int lane = (idx >> 3) & 63, j = idx & 7;
            const int g = lane >> 4, r = lane & 3;    // region = i&3
            const int c = ks * 32 + g * 8 + j;
            mwT[idx] = f2bf(mw[(r * 64 + c) * 9 + tap]);
        }
    }
}

// ---------------------------------------------------------------------------
// fused: dynamic grouped conv + mask conv/softmax + region sum + BN + ReLU.
// Round 7 = round-6 resubmit (container infra failure, kernel audited clean).
// fm-split for TLP: each block covers 32 output channels (oh half); grid
// doubles to 1024 blocks -> 3 blocks/CU resident (12 waves/CU, was 8).
// fm-split keeps A-bytes/MFMA at 256B (the r3 fn-split doubled it) and
// shrinks the live set (o_acc 32, A-dbuf 32) to fit the (256,3) 170-reg cap
// without spill (r4 lesson: never force occupancy past the live set).
// LDS 3 x 51.2KB = 153.6 <= 160KB.
// ---------------------------------------------------------------------------
#define XS_W     66                      // 64 + 2 halo columns
#define XS_ROWS  6                       // 4 output rows + 2 halo rows
#define XS_ELEMS (XS_ROWS * XS_W * 64)   // 25344 shorts = 50.7 KB, swizzled

__global__ __launch_bounds__(256, 3) void main_conv(
        const unsigned short* __restrict__ xT,
        const unsigned short* __restrict__ kT,
        const unsigned short* __restrict__ mwT,
        const float* __restrict__ mb,
        const float* __restrict__ bn_gamma, const float* __restrict__ bn_beta,
        const float* __restrict__ bn_mean,  const float* __restrict__ bn_var,
        float* __restrict__ outp, float* __restrict__ masks_g) {
    __shared__ __align__(16) unsigned short xs[XS_ELEMS];
    __shared__ float scale_s[COUT];
    __shared__ float shift_s[COUT];

    const int tid = threadIdx.x;
    const int b  = blockIdx.z >> 1;
    const int oh = blockIdx.z & 1;            // output-channel half: fm = oh*2+{0,1}
    const int w0 = blockIdx.y << 6;           // 0 or 64
    const int h0 = blockIdx.x << 2;           // 0..124
    const int lane = tid & 63, wv = tid >> 6; // wave wv owns output row h0+wv
    const int i = lane & 15, g = lane >> 4;
    const int h_out = h0 + wv;

    // ---- stage x halo tile, XOR-swizzled: slot' = slot ^ (rw&7) ----
    const unsigned short* xb = xT + (size_t)b * (HW_ * CIN);
    #pragma unroll
    for (int row = 0; row < XS_ROWS; row++) {
        const int h_in = h0 - 1 + row;
        const bool hok = (h_in >= 0) && (h_in < H_);
        for (int idx = tid; idx < XS_W * 8; idx += 256) {
            const int w = idx >> 3, c8 = (idx & 7) << 3;
            const int w_in = w0 - 1 + w;
            int4 v = make_int4(0, 0, 0, 0);
            if (hok && (w_in >= 0) && (w_in < W_))
                v = *(const int4*)(xb + ((h_in * W_ + w_in) << 6) + c8);
            const int rw = row * XS_W + w;
            *(int4*)(&xs[(rw << 6) + (((c8 >> 3) ^ (rw & 7)) << 3)]) = v;
        }
    }
    if (tid < COUT) {
        const float sc = bn_gamma[tid] * rsqrtf(bn_var[tid] + BN_EPS);
        scale_s[tid] = sc;
        shift_s[tid] = bn_beta[tid] - bn_mean[tid] * sc;
    }
    const float mb0 = mb[0], mb1 = mb[1], mb2 = mb[2], mb3 = mb[3];

    __syncthreads();                          // the ONLY barrier in this kernel

    // ---- logits pre-pass: 9 taps, A = mwT from global, softmax -> masks ----
    // Both oc-halves compute the masks (needed for Horner); only oh==0 stores.
    v4f lg_acc[4];
    #pragma unroll
    for (int fn = 0; fn < 4; fn++) lg_acc[fn] = (v4f){0.f, 0.f, 0.f, 0.f};
    for (int tap = 0; tap < 9; tap++) {
        const int rwb = (wv + tap / 3) * XS_W + i + tap % 3;
        const int base = (rwb << 6) + ((g ^ (rwb & 7)) << 3);
        #pragma unroll
        for (int ks = 0; ks < 2; ks++) {
            const v8s am = *(const v8s*)(mwT + (((tap * 2 + ks) << 9) + (lane << 3)));
            #pragma unroll
            for (int fn = 0; fn < 4; fn++) {
                const v8s bv = *(const v8s*)(&xs[(base + (fn << 10)) ^ (ks << 5)]);
                lg_acc[fn] = __builtin_amdgcn_mfma_f32_16x16x32_bf16(am, bv, lg_acc[fn], 0, 0, 0);
            }
        }
    }
    unsigned mk0[4], mk1[4];                  // bf16-packed clamped masks (r0|r1),(r2|r3)
    #pragma unroll
    for (int fn = 0; fn < 4; fn++) {
        const float l0 = lg_acc[fn][0] + mb0, l1 = lg_acc[fn][1] + mb1;
        const float l2 = lg_acc[fn][2] + mb2, l3 = lg_acc[fn][3] + mb3;
        const float mx = fmaxf(fmaxf(l0, l1), fmaxf(l2, l3));
        const float e0 = __expf(l0 - mx), e1 = __expf(l1 - mx);
        const float e2 = __expf(l2 - mx), e3 = __expf(l3 - mx);
        const float inv = 1.f / (e0 + e1 + e2 + e3);
        const float m0 = e0 * inv, m1 = e1 * inv, m2 = e2 * inv, m3 = e3 * inv;
        if (oh == 0 && g == 0) {              // lanes 0..15 hold valid rows 0..3
            float* mp = masks_g + ((size_t)b * RN_ * H_ + h_out) * W_ + w0 + fn * 16 + i;
            mp[0] = m0; mp[HW_] = m1; mp[2 * HW_] = m2; mp[3 * HW_] = m3;
        }
        mk0[fn] = f2bf(fmaxf(m0, 1e-12f)) | ((unsigned)f2bf(fmaxf(m1, 1e-12f)) << 16);
        mk1[fn] = f2bf(fmaxf(m2, 1e-12f)) | ((unsigned)f2bf(fmaxf(m3, 1e-12f)) << 16);
    }
    // broadcast masks from g==0 lanes to the whole wave (once, not per fold)
    #pragma unroll
    for (int fn = 0; fn < 4; fn++) {
        mk0[fn] = __shfl(mk0[fn], i);
        mk1[fn] = __shfl(mk1[fn], i);
    }
    auto mval = [&](int fn, int rr) -> float {
        const unsigned pk = (rr & 2) ? mk1[fn] : mk0[fn];
        return (rr & 1) ? __uint_as_float(pk & 0xffff0000u)
                        : __uint_as_float(pk << 16);
    };

    // ---- main loop: A (this oc-half only) dbuf from global, B dbuf 1 tap ahead ----
    const unsigned short* kb = kT + (size_t)b * (36 * 4096) + (oh << 11) + (lane << 3);
    v4f o_acc[2][4];
    #pragma unroll
    for (int fm = 0; fm < 2; fm++)
        #pragma unroll
        for (int fn = 0; fn < 4; fn++)
            o_acc[fm][fn] = (v4f){0.f, 0.f, 0.f, 0.f};

    v8s aA[4], aB[4], b0[8], b1[8];
    auto lda = [&](v8s (&dst)[4], int t) {
        const unsigned short* kp = kb + ((size_t)t << 12);
        #pragma unroll
        for (int q = 0; q < 4; q++) dst[q] = *(const v8s*)(kp + (q << 9));
    };
    auto ldb = [&](v8s (&dst)[8], int t) {    // both ks halves of one tap
        const int rwb = (wv + t / 3) * XS_W + i + t % 3;
        const int base = (rwb << 6) + ((g ^ (rwb & 7)) << 3);
        #pragma unroll
        for (int fn = 0; fn < 4; fn++) {
            dst[fn]     = *(const v8s*)(&xs[base + (fn << 10)]);
            dst[4 + fn] = *(const v8s*)(&xs[(base + (fn << 10)) ^ 32]);
        }
    };

    lda(aA, 0); lda(aB, 1);
    ldb(b0, 0);

    int tap = 0, r = 0;
    auto step = [&](const v8s (&ac)[4], const v8s (&bc)[8], v8s (&bn)[8]) {
        const int ntap = (tap == 8) ? 0 : tap + 1;
        ldb(bn, ntap);                        // prefetch next tap's B-frags
        __builtin_amdgcn_s_setprio(1);
        #pragma unroll
        for (int ks = 0; ks < 2; ks++)
            #pragma unroll
            for (int fm = 0; fm < 2; fm++)
                #pragma unroll
                for (int fn = 0; fn < 4; fn++)
                    o_acc[fm][fn] = __builtin_amdgcn_mfma_f32_16x16x32_bf16(
                        ac[fm * 2 + ks], bc[ks * 4 + fn], o_acc[fm][fn], 0, 0, 0);
        __builtin_amdgcn_s_setprio(0);
        if (++tap == 9) {                     // region done: Horner fold
            tap = 0;
            if (r < 3) {
                #pragma unroll
                for (int fn = 0; fn < 4; fn++) {
                    const float ratio = mval(fn, r) / mval(fn, r + 1);
                    #pragma unroll
                    for (int fm = 0; fm < 2; fm++)
                        #pragma unroll
                        for (int c = 0; c < 4; c++)
                            o_acc[fm][fn][c] *= ratio;
                }
            }
            r++;
        }
    };

    for (int rt = 0; rt < 36; rt += 2) {
        step(aA, b0, b1);
        if (rt + 2 < 36) lda(aA, rt + 2);
        step(aB, b1, b0);
        if (rt + 3 < 36) lda(aB, rt + 3);
    }

    // ---- epilogue: *m3 (Horner final), BN + ReLU + store ----
    float mv3[4];
    #pragma unroll
    for (int fn = 0; fn < 4; fn++) mv3[fn] = mval(fn, 3);
    #pragma unroll
    for (int fm = 0; fm < 2; fm++) {
        #pragma unroll
        for (int reg = 0; reg < 4; reg++) {
            const int o = (oh * 2 + fm) * 16 + g * 4 + reg;
            const float sc = scale_s[o], sh = shift_s[o];
            float* rowp = outp + (((size_t)b * COUT + o) * H_ + h_out) * W_ + w0 + i;
            #pragma unroll
            for (int fn = 0; fn < 4; fn++) {
                const float v = o_acc[fm][fn][reg] * mv3[fn] * sc + sh;
                rowp[fn * 16] = fmaxf(v, 0.f);
            }
        }
    }
}

// ---------------------------------------------------------------------------
extern "C" void kernel_launch(void* const* d_in, const int* in_sizes, int n_in,
                              void* d_out, int out_size, void* d_ws, size_t ws_size,
                              hipStream_t stream) {
    const float* x     = (const float*)d_in[0];
    const float* kr    = (const float*)d_in[1];
    const float* mw    = (const float*)d_in[2];
    const float* mb    = (const float*)d_in[3];
    const float* gamma = (const float*)d_in[4];
    const float* beta  = (const float*)d_in[5];
    const float* mean  = (const float*)d_in[6];
    const float* var   = (const float*)d_in[7];

    float* outp  = (float*)d_out;
    float* masks = outp + (size_t)B_ * COUT * HW_;          // output #2 region

    unsigned short* xT  = (unsigned short*)d_ws;            // 16 MiB
    unsigned short* kT  = xT + (size_t)B_ * HW_ * CIN;      // +2.25 MiB
    unsigned short* mwT = kT + (size_t)B_ * RN_ * 9 * 4096; // +18 KiB

    hipLaunchKernelGGL(prep, dim3(1153), dim3(256), 0, stream, x, kr, mw, xT, kT, mwT);
    hipLaunchKernelGGL(main_conv, dim3(H_ / 4, 2, B_ * 2), dim3(256), 0, stream,
                       xT, kT, mwT, mb, gamma, beta, mean, var, outp, masks);
}

// Round 8
// 141.143 us; speedup vs baseline: 1.0434x; 1.0434x over previous
//
#include <hip/hip_runtime.h>
#include <hip/hip_bf16.h>

#define B_    8
#define CIN   64
#define COUT  64
#define RN_   4
#define H_    128
#define W_    128
#define HW_   (H_ * W_)
#define BN_EPS 1e-5f

typedef short v8s __attribute__((ext_vector_type(8)));
typedef float v4f __attribute__((ext_vector_type(4)));

__device__ __forceinline__ unsigned short f2bf(float f) {
    unsigned int u = __float_as_uint(f);
    u += 0x7FFFu + ((u >> 16) & 1u);       // round-to-nearest-even
    return (unsigned short)(u >> 16);
}

// ---------------------------------------------------------------------------
// prep: merged transpose kernels (one launch)
//   blocks [0,1024):    x fp32 [b][c][h][w] -> xT bf16 [b][h][w][c]
//   blocks [1024,1152): kernel fp32 -> kT bf16 in MFMA A-fragment order
//   block  1152:        mask weights fp32 [r][c][t] -> mwT bf16 in A-frag
//                       order (region replicated to rows r, r+4, r+8, r+12)
// ---------------------------------------------------------------------------
__global__ __launch_bounds__(256) void prep(const float* __restrict__ x,
                                            const float* __restrict__ kr,
                                            const float* __restrict__ mw,
                                            unsigned short* __restrict__ xT,
                                            unsigned short* __restrict__ kT,
                                            unsigned short* __restrict__ mwT) {
    __shared__ float sl[16 * 64 * 9];                 // 36 KB (union of both uses)
    if (blockIdx.x < 1024) {
        const int b = blockIdx.x >> 7, h = blockIdx.x & 127;
        const float* xp = x + (size_t)b * CIN * HW_ + (size_t)h * W_;
        for (int idx = threadIdx.x; idx < CIN * (W_ / 4); idx += 256) {
            const int c = idx >> 5, w4 = (idx & 31) << 2;   // float4 loads (G13)
            const float4 v = *(const float4*)(xp + (size_t)c * HW_ + w4);
            float* s = &sl[c * 129 + w4];                   // 129-pad: conflict-free col reads
            s[0] = v.x; s[1] = v.y; s[2] = v.z; s[3] = v.w;
        }
        __syncthreads();
        unsigned short* op = xT + ((size_t)b * H_ + h) * (W_ * CIN);
        for (int idx = threadIdx.x; idx < (W_ * CIN) / 8; idx += 256) {
            const int w = idx >> 3, c0 = (idx & 7) << 3;
            int4 v;
            v.x = f2bf(sl[(c0 + 0) * 129 + w]) | ((unsigned)f2bf(sl[(c0 + 1) * 129 + w]) << 16);
            v.y = f2bf(sl[(c0 + 2) * 129 + w]) | ((unsigned)f2bf(sl[(c0 + 3) * 129 + w]) << 16);
            v.z = f2bf(sl[(c0 + 4) * 129 + w]) | ((unsigned)f2bf(sl[(c0 + 5) * 129 + w]) << 16);
            v.w = f2bf(sl[(c0 + 6) * 129 + w]) | ((unsigned)f2bf(sl[(c0 + 7) * 129 + w]) << 16);
            *(int4*)(op + (w << 6) + c0) = v;
        }
    } else if (blockIdx.x < 1152) {
        const int bid = blockIdx.x - 1024;
        const int br = bid >> 2, oq = bid & 3;        // br = b*4+r; oq = 16-o chunk
        const float* src = kr + ((size_t)br * 64 + oq * 16) * (64 * 9);
        for (int idx = threadIdx.x; idx < 2304; idx += 256)
            *(float4*)&sl[idx << 2] = *(const float4*)&src[idx << 2];
        __syncthreads();
        unsigned short* dst = kT + (size_t)br * (9 * 4096);
        for (int idx = threadIdx.x; idx < 1152; idx += 256) {
            const int t = idx >> 7, rem = idx & 127, o16 = rem >> 3, c8 = (rem & 7) << 3;
            unsigned short s[8];
            #pragma unroll
            for (int j = 0; j < 8; j++)
                s[j] = f2bf(sl[(o16 * 64 + c8 + j) * 9 + t]);
            int4 v;
            v.x = s[0] | ((unsigned)s[1] << 16);
            v.y = s[2] | ((unsigned)s[3] << 16);
            v.z = s[4] | ((unsigned)s[5] << 16);
            v.w = s[6] | ((unsigned)s[7] << 16);
            // fragment order: o = oq*16+o16 -> fm=oq, i=o16 ; c = c8+j -> ks=c8>>5, g=(c8>>3)&3
            const int q  = oq * 2 + (c8 >> 5);        // frag index fm*2+ks
            const int gg = (c8 >> 3) & 3;             // g
            *(int4*)(dst + (size_t)t * 4096 + q * 512 + (gg * 16 + o16) * 8) = v;
        }
    } else {
        // mwT[tile=tap*2+ks][lane][8]: lane=(g<<4)|i, row i holds region i&3
        for (int idx = threadIdx.x; idx < 9 * 2 * 64 * 8; idx += 256) {
            const int tile = idx >> 9;                // tap*2+ks
            const int tap = tile >> 1, ks = tile & 1;
            const int lane = (idx >> 3) & 63, j = idx & 7;
            const int g = lane >> 4, r = lane & 3;    // region = i&3
            const int c = ks * 32 + g * 8 + j;
            mwT[idx] = f2bf(mw[(r * 64 + c) * 9 + tap]);
        }
    }
}

// ---------------------------------------------------------------------------
// fused: dynamic grouped conv + mask conv/softmax + region sum + BN + ReLU.
// Round 8 = r5 structure (best: 45.1us) fully unrolled + hoisted:
//   - all 36 K-steps unrolled (4 regions x 9 taps): tap/3, tap%3, buffer
//     selection, Horner indexing all become compile-time (r5 paid runtime
//     integer-div magic-mul sequences + branches every step -> VALUBusy 24%)
//   - 9 per-tap swizzled LDS byte-bases (+ ^64 ks-twins) hoisted to regs:
//     ds_reads become base-reg + immediate offset
//   - Horner ratios (12 f32 divides) precomputed off the hot path
// Register estimate ~220 unified < 256 -> still 2 blocks/CU, no spill.
// ---------------------------------------------------------------------------
#define XS_W     66                      // 64 + 2 halo columns
#define XS_ROWS  6                       // 4 output rows + 2 halo rows
#define XS_ELEMS (XS_ROWS * XS_W * 64)   // 25344 shorts = 50.7 KB, swizzled

__global__ __launch_bounds__(256, 2) void main_conv(
        const unsigned short* __restrict__ xT,
        const unsigned short* __restrict__ kT,
        const unsigned short* __restrict__ mwT,
        const float* __restrict__ mb,
        const float* __restrict__ bn_gamma, const float* __restrict__ bn_beta,
        const float* __restrict__ bn_mean,  const float* __restrict__ bn_var,
        float* __restrict__ outp, float* __restrict__ masks_g) {
    __shared__ __align__(16) unsigned short xs[XS_ELEMS];
    __shared__ float scale_s[COUT];
    __shared__ float shift_s[COUT];

    const int tid = threadIdx.x;
    const int b  = blockIdx.z;
    const int w0 = blockIdx.y << 6;           // 0 or 64
    const int h0 = blockIdx.x << 2;           // 0..124
    const int lane = tid & 63, wv = tid >> 6; // wave wv owns output row h0+wv
    const int i = lane & 15, g = lane >> 4;
    const int h_out = h0 + wv;

    // ---- stage x halo tile, XOR-swizzled: slot' = slot ^ (rw&7) ----
    const unsigned short* xb = xT + (size_t)b * (HW_ * CIN);
    #pragma unroll
    for (int row = 0; row < XS_ROWS; row++) {
        const int h_in = h0 - 1 + row;
        const bool hok = (h_in >= 0) && (h_in < H_);
        for (int idx = tid; idx < XS_W * 8; idx += 256) {
            const int w = idx >> 3, c8 = (idx & 7) << 3;
            const int w_in = w0 - 1 + w;
            int4 v = make_int4(0, 0, 0, 0);
            if (hok && (w_in >= 0) && (w_in < W_))
                v = *(const int4*)(xb + ((h_in * W_ + w_in) << 6) + c8);
            const int rw = row * XS_W + w;
            *(int4*)(&xs[(rw << 6) + (((c8 >> 3) ^ (rw & 7)) << 3)]) = v;
        }
    }
    if (tid < COUT) {
        const float sc = bn_gamma[tid] * rsqrtf(bn_var[tid] + BN_EPS);
        scale_s[tid] = sc;
        shift_s[tid] = bn_beta[tid] - bn_mean[tid] * sc;
    }
    const float mb0 = mb[0], mb1 = mb[1], mb2 = mb[2], mb3 = mb[3];

    // ---- hoisted per-tap swizzled LDS byte-bases (ks=0 and ks=1 twins) ----
    int tbB[9], txB[9];
    #pragma unroll
    for (int t = 0; t < 9; t++) {
        const int rwb = (wv + t / 3) * XS_W + i + t % 3;      // compile-time t
        const int e = (rwb << 6) + ((g ^ (rwb & 7)) << 3);
        tbB[t] = e << 1;               // byte offset
        txB[t] = (e << 1) ^ 64;        // ks=1: ^32 shorts = ^64 bytes (bit6 safe)
    }
    const char* xsc = (const char*)xs;

    __syncthreads();                          // the ONLY barrier in this kernel

    // ---- logits pre-pass: 9 taps, A = mwT from global, softmax -> masks ----
    v4f lg_acc[4];
    #pragma unroll
    for (int fn = 0; fn < 4; fn++) lg_acc[fn] = (v4f){0.f, 0.f, 0.f, 0.f};
    #pragma unroll
    for (int tap = 0; tap < 9; tap++) {
        #pragma unroll
        for (int ks = 0; ks < 2; ks++) {
            const v8s am = *(const v8s*)(mwT + (((tap * 2 + ks) << 9) + (lane << 3)));
            #pragma unroll
            for (int fn = 0; fn < 4; fn++) {
                const v8s bv = *(const v8s*)(xsc + (ks ? txB[tap] : tbB[tap]) + (fn << 11));
                lg_acc[fn] = __builtin_amdgcn_mfma_f32_16x16x32_bf16(am, bv, lg_acc[fn], 0, 0, 0);
            }
        }
    }
    unsigned mk0[4], mk1[4];                  // bf16-packed clamped masks (r0|r1),(r2|r3)
    #pragma unroll
    for (int fn = 0; fn < 4; fn++) {
        const float l0 = lg_acc[fn][0] + mb0, l1 = lg_acc[fn][1] + mb1;
        const float l2 = lg_acc[fn][2] + mb2, l3 = lg_acc[fn][3] + mb3;
        const float mx = fmaxf(fmaxf(l0, l1), fmaxf(l2, l3));
        const float e0 = __expf(l0 - mx), e1 = __expf(l1 - mx);
        const float e2 = __expf(l2 - mx), e3 = __expf(l3 - mx);
        const float inv = 1.f / (e0 + e1 + e2 + e3);
        const float m0 = e0 * inv, m1 = e1 * inv, m2 = e2 * inv, m3 = e3 * inv;
        if (g == 0) {                         // lanes 0..15 hold valid rows 0..3
            float* mp = masks_g + ((size_t)b * RN_ * H_ + h_out) * W_ + w0 + fn * 16 + i;
            mp[0] = m0; mp[HW_] = m1; mp[2 * HW_] = m2; mp[3 * HW_] = m3;
        }
        mk0[fn] = f2bf(fmaxf(m0, 1e-12f)) | ((unsigned)f2bf(fmaxf(m1, 1e-12f)) << 16);
        mk1[fn] = f2bf(fmaxf(m2, 1e-12f)) | ((unsigned)f2bf(fmaxf(m3, 1e-12f)) << 16);
    }
    // broadcast masks from g==0 lanes; precompute Horner ratios off hot path
    float rat[3][4], mv3[4];
    #pragma unroll
    for (int fn = 0; fn < 4; fn++) {
        mk0[fn] = __shfl(mk0[fn], i);
        mk1[fn] = __shfl(mk1[fn], i);
        const float q0 = __uint_as_float(mk0[fn] << 16);
        const float q1 = __uint_as_float(mk0[fn] & 0xffff0000u);
        const float q2 = __uint_as_float(mk1[fn] << 16);
        const float q3 = __uint_as_float(mk1[fn] & 0xffff0000u);
        rat[0][fn] = q0 / q1; rat[1][fn] = q1 / q2; rat[2][fn] = q2 / q3;
        mv3[fn] = q3;
    }

    // ---- main loop: FULLY UNROLLED 36 steps; A 2-deep dbuf from global,
    //      B 1-tap-ahead dbuf from LDS; all indices compile-time ----
    const unsigned short* kb = kT + (size_t)b * (36 * 4096) + (lane << 3);
    v4f o_acc[4][4];
    #pragma unroll
    for (int fm = 0; fm < 4; fm++)
        #pragma unroll
        for (int fn = 0; fn < 4; fn++)
            o_acc[fm][fn] = (v4f){0.f, 0.f, 0.f, 0.f};

    v8s abuf[2][8], bbuf[2][8];
    #pragma unroll
    for (int p = 0; p < 2; p++)
        #pragma unroll
        for (int q = 0; q < 8; q++)
            abuf[p][q] = *(const v8s*)(kb + ((size_t)p << 12) + (q << 9));
    #pragma unroll
    for (int fn = 0; fn < 4; fn++) {
        bbuf[0][fn]     = *(const v8s*)(xsc + tbB[0] + (fn << 11));
        bbuf[0][4 + fn] = *(const v8s*)(xsc + txB[0] + (fn << 11));
    }

    #pragma unroll
    for (int rr = 0; rr < 4; rr++) {
        #pragma unroll
        for (int t = 0; t < 9; t++) {
            const int s  = rr * 9 + t;        // compile-time
            const int cb = s & 1, nb = cb ^ 1, as_ = s & 1;
            const int nt = (t == 8) ? 0 : t + 1;
            // prefetch next tap's B-frags (immediate-offset ds_reads)
            #pragma unroll
            for (int fn = 0; fn < 4; fn++) {
                bbuf[nb][fn]     = *(const v8s*)(xsc + tbB[nt] + (fn << 11));
                bbuf[nb][4 + fn] = *(const v8s*)(xsc + txB[nt] + (fn << 11));
            }
            __builtin_amdgcn_s_setprio(1);
            #pragma unroll
            for (int ks = 0; ks < 2; ks++)
                #pragma unroll
                for (int fm = 0; fm < 4; fm++)
                    #pragma unroll
                    for (int fn = 0; fn < 4; fn++)
                        o_acc[fm][fn] = __builtin_amdgcn_mfma_f32_16x16x32_bf16(
                            abuf[as_][fm * 2 + ks], bbuf[cb][ks * 4 + fn],
                            o_acc[fm][fn], 0, 0, 0);
            __builtin_amdgcn_s_setprio(0);
            if (s + 2 < 36) {                 // refill just-consumed A buffer
                const unsigned short* kp = kb + ((size_t)(s + 2) << 12);
                #pragma unroll
                for (int q = 0; q < 8; q++)
                    abuf[as_][q] = *(const v8s*)(kp + (q << 9));
            }
            if (t == 8 && rr < 3) {           // region done: Horner fold (static rr)
                #pragma unroll
                for (int fn = 0; fn < 4; fn++)
                    #pragma unroll
                    for (int fm = 0; fm < 4; fm++)
                        #pragma unroll
                        for (int c = 0; c < 4; c++)
                            o_acc[fm][fn][c] *= rat[rr][fn];
            }
        }
    }

    // ---- epilogue: *m3 (Horner final), BN + ReLU + store ----
    #pragma unroll
    for (int fm = 0; fm < 4; fm++) {
        #pragma unroll
        for (int reg = 0; reg < 4; reg++) {
            const int o = fm * 16 + g * 4 + reg;
            const float sc = scale_s[o], sh = shift_s[o];
            float* rowp = outp + (((size_t)b * COUT + o) * H_ + h_out) * W_ + w0 + i;
            #pragma unroll
            for (int fn = 0; fn < 4; fn++) {
                const float v = o_acc[fm][fn][reg] * mv3[fn] * sc + sh;
                rowp[fn * 16] = fmaxf(v, 0.f);
            }
        }
    }
}

// ---------------------------------------------------------------------------
extern "C" void kernel_launch(void* const* d_in, const int* in_sizes, int n_in,
                              void* d_out, int out_size, void* d_ws, size_t ws_size,
                              hipStream_t stream) {
    const float* x     = (const float*)d_in[0];
    const float* kr    = (const float*)d_in[1];
    const float* mw    = (const float*)d_in[2];
    const float* mb    = (const float*)d_in[3];
    const float* gamma = (const float*)d_in[4];
    const float* beta  = (const float*)d_in[5];
    const float* mean  = (const float*)d_in[6];
    const float* var   = (const float*)d_in[7];

    float* outp  = (float*)d_out;
    float* masks = outp + (size_t)B_ * COUT * HW_;          // output #2 region

    unsigned short* xT  = (unsigned short*)d_ws;            // 16 MiB
    unsigned short* kT  = xT + (size_t)B_ * HW_ * CIN;      // +2.25 MiB
    unsigned short* mwT = kT + (size_t)B_ * RN_ * 9 * 4096; // +18 KiB

    hipLaunchKernelGGL(prep, dim3(1153), dim3(256), 0, stream, x, kr, mw, xT, kT, mwT);
    hipLaunchKernelGGL(main_conv, dim3(H_ / 4, 2, B_), dim3(256), 0, stream,
                       xT, kT, mwT, mb, gamma, beta, mean, var, outp, masks);
}

// Round 9
// 138.919 us; speedup vs baseline: 1.0601x; 1.0160x over previous
//
#include <hip/hip_runtime.h>
#include <hip/hip_bf16.h>

#define B_    8
#define CIN   64
#define COUT  64
#define RN_   4
#define H_    128
#define W_    128
#define HW_   (H_ * W_)
#define BN_EPS 1e-5f

typedef short v8s __attribute__((ext_vector_type(8)));
typedef float v4f __attribute__((ext_vector_type(4)));

__device__ __forceinline__ unsigned short f2bf(float f) {
    unsigned int u = __float_as_uint(f);
    u += 0x7FFFu + ((u >> 16) & 1u);       // round-to-nearest-even
    return (unsigned short)(u >> 16);
}

// ---------------------------------------------------------------------------
// prep: merged transpose kernels (one launch) — unchanged layouts
//   blocks [0,1024):    x fp32 [b][c][h][w] -> xT bf16 [b][h][w][c]
//   blocks [1024,1152): kernel fp32 -> kT bf16 in MFMA A-fragment order
//   block  1152:        mask weights fp32 [r][c][t] -> mwT bf16 A-frag order
// ---------------------------------------------------------------------------
__global__ __launch_bounds__(256) void prep(const float* __restrict__ x,
                                            const float* __restrict__ kr,
                                            const float* __restrict__ mw,
                                            unsigned short* __restrict__ xT,
                                            unsigned short* __restrict__ kT,
                                            unsigned short* __restrict__ mwT) {
    __shared__ float sl[16 * 64 * 9];                 // 36 KB (union of both uses)
    if (blockIdx.x < 1024) {
        const int b = blockIdx.x >> 7, h = blockIdx.x & 127;
        const float* xp = x + (size_t)b * CIN * HW_ + (size_t)h * W_;
        for (int idx = threadIdx.x; idx < CIN * (W_ / 4); idx += 256) {
            const int c = idx >> 5, w4 = (idx & 31) << 2;   // float4 loads (G13)
            const float4 v = *(const float4*)(xp + (size_t)c * HW_ + w4);
            float* s = &sl[c * 129 + w4];                   // 129-pad: conflict-free col reads
            s[0] = v.x; s[1] = v.y; s[2] = v.z; s[3] = v.w;
        }
        __syncthreads();
        unsigned short* op = xT + ((size_t)b * H_ + h) * (W_ * CIN);
        for (int idx = threadIdx.x; idx < (W_ * CIN) / 8; idx += 256) {
            const int w = idx >> 3, c0 = (idx & 7) << 3;
            int4 v;
            v.x = f2bf(sl[(c0 + 0) * 129 + w]) | ((unsigned)f2bf(sl[(c0 + 1) * 129 + w]) << 16);
            v.y = f2bf(sl[(c0 + 2) * 129 + w]) | ((unsigned)f2bf(sl[(c0 + 3) * 129 + w]) << 16);
            v.z = f2bf(sl[(c0 + 4) * 129 + w]) | ((unsigned)f2bf(sl[(c0 + 5) * 129 + w]) << 16);
            v.w = f2bf(sl[(c0 + 6) * 129 + w]) | ((unsigned)f2bf(sl[(c0 + 7) * 129 + w]) << 16);
            *(int4*)(op + (w << 6) + c0) = v;
        }
    } else if (blockIdx.x < 1152) {
        const int bid = blockIdx.x - 1024;
        const int br = bid >> 2, oq = bid & 3;        // br = b*4+r; oq = 16-o chunk
        const float* src = kr + ((size_t)br * 64 + oq * 16) * (64 * 9);
        for (int idx = threadIdx.x; idx < 2304; idx += 256)
            *(float4*)&sl[idx << 2] = *(const float4*)&src[idx << 2];
        __syncthreads();
        unsigned short* dst = kT + (size_t)br * (9 * 4096);
        for (int idx = threadIdx.x; idx < 1152; idx += 256) {
            const int t = idx >> 7, rem = idx & 127, o16 = rem >> 3, c8 = (rem & 7) << 3;
            unsigned short s[8];
            #pragma unroll
            for (int j = 0; j < 8; j++)
                s[j] = f2bf(sl[(o16 * 64 + c8 + j) * 9 + t]);
            int4 v;
            v.x = s[0] | ((unsigned)s[1] << 16);
            v.y = s[2] | ((unsigned)s[3] << 16);
            v.z = s[4] | ((unsigned)s[5] << 16);
            v.w = s[6] | ((unsigned)s[7] << 16);
            // fragment order: o = oq*16+o16 -> fm=oq, i=o16 ; c = c8+j -> ks=c8>>5, g=(c8>>3)&3
            const int q  = oq * 2 + (c8 >> 5);        // frag index fm*2+ks
            const int gg = (c8 >> 3) & 3;             // g
            *(int4*)(dst + (size_t)t * 4096 + q * 512 + (gg * 16 + o16) * 8) = v;
        }
    } else {
        // mwT[tile=tap*2+ks][lane][8]: lane=(g<<4)|i, row i holds region i&3
        for (int idx = threadIdx.x; idx < 9 * 2 * 64 * 8; idx += 256) {
            const int tile = idx >> 9;                // tap*2+ks
            const int tap = tile >> 1, ks = tile & 1;
            const int lane = (idx >> 3) & 63, j = idx & 7;
            const int g = lane >> 4, r = lane & 3;    // region = i&3
            const int c = ks * 32 + g * 8 + j;
            mwT[idx] = f2bf(mw[(r * 64 + c) * 9 + tap]);
        }
    }
}

// ---------------------------------------------------------------------------
// fused: dynamic grouped conv + mask conv/softmax + region sum + BN + ReLU.
// Round 9: 2-row x fm-half blocks for real TLP. 4 waves = {row0/1} x
// {ch 0-31 / 32-63}. Per wave/step: 16 MFMA, 4 A-frags (A-bytes/MFMA stays
// 256B - avoids r3 trap), 8 B ds_reads (JIT - 3-wave TLP covers LDS lat).
// o_acc 32 + abuf 32 regs -> live ~140 fits (256,3)'s 170 cap naturally
// (r4 lesson: no forced squeeze). LDS 33.8KB -> 3 blocks/CU. Grid 1024
// blocks -> 12 waves/CU (3/SIMD), 1.5x the TLP of every 45us variant.
// ---------------------------------------------------------------------------
#define XS_W     66                      // 64 + 2 halo columns
#define XS_ROWS  4                       // 2 output rows + 2 halo rows
#define XS_ELEMS (XS_ROWS * XS_W * 64)   // 16896 shorts = 33.8 KB, swizzled

__global__ __launch_bounds__(256, 3) void main_conv(
        const unsigned short* __restrict__ xT,
        const unsigned short* __restrict__ kT,
        const unsigned short* __restrict__ mwT,
        const float* __restrict__ mb,
        const float* __restrict__ bn_gamma, const float* __restrict__ bn_beta,
        const float* __restrict__ bn_mean,  const float* __restrict__ bn_var,
        float* __restrict__ outp, float* __restrict__ masks_g) {
    __shared__ __align__(16) unsigned short xs[XS_ELEMS];
    __shared__ float scale_s[COUT];
    __shared__ float shift_s[COUT];

    const int tid = threadIdx.x;
    const int b  = blockIdx.z;
    const int w0 = blockIdx.y << 6;           // 0 or 64
    const int h0 = blockIdx.x << 1;           // 0..126 (2 rows/block)
    const int lane = tid & 63, wv = tid >> 6;
    const int row = wv & 1;                   // output row within block
    const int fmh = wv >> 1;                  // output-channel half (0: ch0-31, 1: ch32-63)
    const int i = lane & 15, g = lane >> 4;
    const int h_out = h0 + row;

    // ---- stage x halo tile (4 rows), XOR-swizzled: slot' = slot ^ (rw&7) ----
    const unsigned short* xb = xT + (size_t)b * (HW_ * CIN);
    #pragma unroll
    for (int rws = 0; rws < XS_ROWS; rws++) {
        const int h_in = h0 - 1 + rws;
        const bool hok = (h_in >= 0) && (h_in < H_);
        for (int idx = tid; idx < XS_W * 8; idx += 256) {
            const int w = idx >> 3, c8 = (idx & 7) << 3;
            const int w_in = w0 - 1 + w;
            int4 v = make_int4(0, 0, 0, 0);
            if (hok && (w_in >= 0) && (w_in < W_))
                v = *(const int4*)(xb + ((h_in * W_ + w_in) << 6) + c8);
            const int rw = rws * XS_W + w;
            *(int4*)(&xs[(rw << 6) + (((c8 >> 3) ^ (rw & 7)) << 3)]) = v;
        }
    }
    if (tid < COUT) {
        const float sc = bn_gamma[tid] * rsqrtf(bn_var[tid] + BN_EPS);
        scale_s[tid] = sc;
        shift_s[tid] = bn_beta[tid] - bn_mean[tid] * sc;
    }
    const float mb0 = mb[0], mb1 = mb[1], mb2 = mb[2], mb3 = mb[3];

    // ---- hoisted per-tap swizzled LDS byte-bases (ks=1 twin = ^64) ----
    int tbB[9];
    #pragma unroll
    for (int t = 0; t < 9; t++) {
        const int rwb = (row + t / 3) * XS_W + i + t % 3;     // compile-time t
        tbB[t] = ((rwb << 6) + ((g ^ (rwb & 7)) << 3)) << 1;  // byte offset
    }
    const char* xsc = (const char*)xs;

    __syncthreads();                          // the ONLY barrier in this kernel

    // ---- logits pre-pass: 9 taps, A = mwT global; both fm-halves compute ----
    v4f lg_acc[4];
    #pragma unroll
    for (int fn = 0; fn < 4; fn++) lg_acc[fn] = (v4f){0.f, 0.f, 0.f, 0.f};
    #pragma unroll
    for (int tap = 0; tap < 9; tap++) {
        #pragma unroll
        for (int ks = 0; ks < 2; ks++) {
            const v8s am = *(const v8s*)(mwT + (((tap * 2 + ks) << 9) + (lane << 3)));
            #pragma unroll
            for (int fn = 0; fn < 4; fn++) {
                const v8s bv = *(const v8s*)(xsc + ((tbB[tap] + (fn << 11)) ^ (ks << 6)));
                lg_acc[fn] = __builtin_amdgcn_mfma_f32_16x16x32_bf16(am, bv, lg_acc[fn], 0, 0, 0);
            }
        }
    }
    unsigned mk0[4], mk1[4];                  // bf16-packed clamped masks (r0|r1),(r2|r3)
    #pragma unroll
    for (int fn = 0; fn < 4; fn++) {
        const float l0 = lg_acc[fn][0] + mb0, l1 = lg_acc[fn][1] + mb1;
        const float l2 = lg_acc[fn][2] + mb2, l3 = lg_acc[fn][3] + mb3;
        const float mx = fmaxf(fmaxf(l0, l1), fmaxf(l2, l3));
        const float e0 = __expf(l0 - mx), e1 = __expf(l1 - mx);
        const float e2 = __expf(l2 - mx), e3 = __expf(l3 - mx);
        const float inv = 1.f / (e0 + e1 + e2 + e3);
        const float m0 = e0 * inv, m1 = e1 * inv, m2 = e2 * inv, m3 = e3 * inv;
        if (fmh == 0 && g == 0) {             // lanes 0..15 hold valid rows 0..3
            float* mp = masks_g + ((size_t)b * RN_ * H_ + h_out) * W_ + w0 + fn * 16 + i;
            mp[0] = m0; mp[HW_] = m1; mp[2 * HW_] = m2; mp[3 * HW_] = m3;
        }
        mk0[fn] = f2bf(fmaxf(m0, 1e-12f)) | ((unsigned)f2bf(fmaxf(m1, 1e-12f)) << 16);
        mk1[fn] = f2bf(fmaxf(m2, 1e-12f)) | ((unsigned)f2bf(fmaxf(m3, 1e-12f)) << 16);
    }
    #pragma unroll
    for (int fn = 0; fn < 4; fn++) {          // broadcast from g==0 lane of col i
        mk0[fn] = __shfl(mk0[fn], i);
        mk1[fn] = __shfl(mk1[fn], i);
    }
    auto mval = [&](int fn, int rr) -> float {    // rr compile-time at all uses
        const unsigned pk = (rr & 2) ? mk1[fn] : mk0[fn];
        return (rr & 1) ? __uint_as_float(pk & 0xffff0000u)
                        : __uint_as_float(pk << 16);
    };

    // ---- main loop: FULLY UNROLLED 36 steps; A (this fm-half: 4 frags)
    //      2-deep reg dbuf from global; B JIT ds_reads (TLP covers) ----
    const unsigned short* kb = kT + (size_t)b * (36 * 4096) + (fmh << 11) + (lane << 3);
    v4f o_acc[2][4];
    #pragma unroll
    for (int fm = 0; fm < 2; fm++)
        #pragma unroll
        for (int fn = 0; fn < 4; fn++)
            o_acc[fm][fn] = (v4f){0.f, 0.f, 0.f, 0.f};

    v8s abuf[2][4];
    #pragma unroll
    for (int p = 0; p < 2; p++)
        #pragma unroll
        for (int q = 0; q < 4; q++)
            abuf[p][q] = *(const v8s*)(kb + ((size_t)p << 12) + (q << 9));

    #pragma unroll
    for (int rr = 0; rr < 4; rr++) {
        #pragma unroll
        for (int t = 0; t < 9; t++) {
            const int s = rr * 9 + t;         // compile-time
            const int as_ = s & 1;
            v8s bv[8];
            #pragma unroll
            for (int fn = 0; fn < 4; fn++) {
                bv[fn]     = *(const v8s*)(xsc + tbB[t] + (fn << 11));
                bv[4 + fn] = *(const v8s*)(xsc + ((tbB[t] + (fn << 11)) ^ 64));
            }
            __builtin_amdgcn_s_setprio(1);
            #pragma unroll
            for (int ks = 0; ks < 2; ks++)
                #pragma unroll
                for (int fm = 0; fm < 2; fm++)
                    #pragma unroll
                    for (int fn = 0; fn < 4; fn++)
                        o_acc[fm][fn] = __builtin_amdgcn_mfma_f32_16x16x32_bf16(
                            abuf[as_][fm * 2 + ks], bv[ks * 4 + fn],
                            o_acc[fm][fn], 0, 0, 0);
            __builtin_amdgcn_s_setprio(0);
            if (s + 2 < 36) {                 // refill just-consumed A buffer
                const unsigned short* kp = kb + ((size_t)(s + 2) << 12);
                #pragma unroll
                for (int q = 0; q < 4; q++)
                    abuf[as_][q] = *(const v8s*)(kp + (q << 9));
            }
            if (t == 8 && rr < 3) {           // region done: Horner fold (static rr)
                #pragma unroll
                for (int fn = 0; fn < 4; fn++) {
                    const float ratio = mval(fn, rr) / mval(fn, rr + 1);
                    #pragma unroll
                    for (int fm = 0; fm < 2; fm++)
                        #pragma unroll
                        for (int c = 0; c < 4; c++)
                            o_acc[fm][fn][c] *= ratio;
                }
            }
        }
    }

    // ---- epilogue: *m3 (Horner final), BN + ReLU + store ----
    #pragma unroll
    for (int fm = 0; fm < 2; fm++) {
        #pragma unroll
        for (int reg = 0; reg < 4; reg++) {
            const int o = fmh * 32 + fm * 16 + g * 4 + reg;
            const float sc = scale_s[o], sh = shift_s[o];
            float* rowp = outp + (((size_t)b * COUT + o) * H_ + h_out) * W_ + w0 + i;
            #pragma unroll
            for (int fn = 0; fn < 4; fn++) {
                const float v = o_acc[fm][fn][reg] * mval(fn, 3) * sc + sh;
                rowp[fn * 16] = fmaxf(v, 0.f);
            }
        }
    }
}

// ---------------------------------------------------------------------------
extern "C" void kernel_launch(void* const* d_in, const int* in_sizes, int n_in,
                              void* d_out, int out_size, void* d_ws, size_t ws_size,
                              hipStream_t stream) {
    const float* x     = (const float*)d_in[0];
    const float* kr    = (const float*)d_in[1];
    const float* mw    = (const float*)d_in[2];
    const float* mb    = (const float*)d_in[3];
    const float* gamma = (const float*)d_in[4];
    const float* beta  = (const float*)d_in[5];
    const float* mean  = (const float*)d_in[6];
    const float* var   = (const float*)d_in[7];

    float* outp  = (float*)d_out;
    float* masks = outp + (size_t)B_ * COUT * HW_;          // output #2 region

    unsigned short* xT  = (unsigned short*)d_ws;            // 16 MiB
    unsigned short* kT  = xT + (size_t)B_ * HW_ * CIN;      // +2.25 MiB
    unsigned short* mwT = kT + (size_t)B_ * RN_ * 9 * 4096; // +18 KiB

    hipLaunchKernelGGL(prep, dim3(1153), dim3(256), 0, stream, x, kr, mw, xT, kT, mwT);
    hipLaunchKernelGGL(main_conv, dim3(H_ / 2, 2, B_), dim3(256), 0, stream,
                       xT, kT, mwT, mb, gamma, beta, mean, var, outp, masks);
}